// Round 15
// baseline (298.637 us; speedup 1.0000x reference)
//
#include <hip/hip_runtime.h>
#include <hip/hip_bf16.h>

#define CIN   512
#define COUT  512
#define LEN   8192
#define NB    16
#define KW    3
#define PROWS 8200           // padded l-rows per plane (prow = l+1)

#define WB_ELEMS (COUT * CIN * KW)
#define WB_BYTES ((size_t)WB_ELEMS * 2)          // 1.5 MB (wb2 packed tiles)
#define PLANEB   ((size_t)PROWS * 16)            // 131200 B per (b,q,kslot) plane
#define XS_BYTES ((size_t)NB * 8 * 8 * PLANEB)   // 128.1 MB

#define XPREP_BLOCKS (NB * 8 * (LEN / 64))   // 16384
#define WCONV_BLOCKS ((WB_ELEMS + 255) / 256)

// main kernel: 256x256 tile, BK=64, 8 waves, r8 schedule, 32x32x16 MFMA,
// k-slot-major LDS layout (conflict-free, swizzle-free)
#define BM2 256
#define BN2 256
#define BK3 64
#define NT  24               // K-tiles, tap innermost

typedef __attribute__((ext_vector_type(4)))  float f32x4;
typedef __attribute__((ext_vector_type(16))) float f32x16;
typedef __attribute__((ext_vector_type(8)))  short bf16x8;

static __device__ __forceinline__ unsigned short f2bf(float f) {
    union { float f; unsigned u; } cv; cv.f = f;
    return (unsigned short)((cv.u + 0x7fffu + ((cv.u >> 16) & 1u)) >> 16);
}

// ---- merged prep ----
// blocks [0,16384): x fp32 [b][ci][l] -> xs2 planes [b][q][kslot][prow][8 bf16]
// blocks [16384,+3072): qweight -> wb2 packed [co_tile][tile][kslot][row][8 bf16]
__global__ __launch_bounds__(256) void prep_kernel(const float* __restrict__ x,
                                                   const int* __restrict__ q,
                                                   char* __restrict__ xs2,
                                                   char* __restrict__ wb2) {
    __shared__ char T[64 * 132];
    int blk = blockIdx.x;
    int tid = threadIdx.x;

    if (blk >= XPREP_BLOCKS) {
        int idx = (blk - XPREP_BLOCKS) * 256 + tid;   // (co, ci, t) order of qweight
        if (idx < WB_ELEMS) {
            int co  = idx / (CIN * KW);
            int rem = idx - co * (CIN * KW);
            int ci  = rem / KW;
            int t   = rem - ci * KW;
            unsigned short v = f2bf((float)q[idx]);
            int cc = (ci >> 6) * KW + t;              // tile index (tap innermost)
            size_t byte = ((size_t)(co >> 8) * NT + cc) * 32768
                        + (size_t)((ci >> 3) & 7) * 4096
                        + (size_t)(co & 255) * 16 + (ci & 7) * 2;
            *(unsigned short*)(wb2 + byte) = v;
        }
        return;
    }

    int b   = blk >> 10;
    int q8  = (blk >> 7) & 7;          // ci chunk (64)
    int l0  = (blk & 127) * 64;
    char* xp = xs2 + ((size_t)(b * 8 + q8) * 8) * PLANEB;

    // zero halo rows (prow 0 and 8193) of this block's 8 kslot planes
    if (l0 == 0 && tid < 8) {
        f32x4 z = {};
        *(f32x4*)(xp + (size_t)tid * PLANEB) = z;
    }
    if (l0 == (LEN - 64) && tid < 8) {
        f32x4 z = {};
        *(f32x4*)(xp + (size_t)tid * PLANEB + (size_t)(LEN + 1) * 16) = z;
    }

    const float* src = x + ((size_t)b * CIN + q8 * 64) * LEN + l0;
    for (int i = tid; i < 64 * 16; i += 256) {
        int r = i >> 4, c4 = i & 15;
        f32x4 v = *(const f32x4*)(src + (size_t)r * LEN + c4 * 4);
        unsigned lo = (unsigned)f2bf(v[0]) | ((unsigned)f2bf(v[1]) << 16);
        unsigned hi = (unsigned)f2bf(v[2]) | ((unsigned)f2bf(v[3]) << 16);
        char* p = T + r * 132 + c4 * 8;
        *(unsigned*)p       = lo;
        *(unsigned*)(p + 4) = hi;
    }
    __syncthreads();
    for (int i = tid; i < 64 * 8; i += 256) {
        int l = i >> 3, c8 = i & 7;
        union { bf16x8 v; unsigned short s[8]; } pk;
        #pragma unroll
        for (int j = 0; j < 8; ++j)
            pk.s[j] = *(const unsigned short*)(T + (c8 * 8 + j) * 132 + l * 2);
        *(bf16x8*)(xp + (size_t)c8 * PLANEB + (size_t)(1 + l0 + l) * 16) = pk.v;
    }
}

// ---- main conv: r8 schedule, 32x32x16 MFMA, kslot-major LDS (no swizzle) ----
__global__ __launch_bounds__(512, 2) void conv_kernel(
    const char* __restrict__ xs2,
    const char* __restrict__ wb2,
    const float* __restrict__ scale_p,
    const float* __restrict__ bias,
    float* __restrict__ out)
{
    __shared__ char sA[2][32768];    // [kslot][row][16B], 2 dbuf
    __shared__ char sB[2][32768];

    const int bid = blockIdx.x;
    const int logical = (bid & 7) * 128 + (bid >> 3);   // XCD swizzle, 1024 = 8*128
    const int co_tile = logical & 1;
    const int l_tile  = logical >> 1;
    const int b   = l_tile >> 5;
    const int l0  = (l_tile & 31) * BN2;
    const int co0 = co_tile * BM2;

    const int tid  = threadIdx.x;
    const int lane = tid & 63;
    const int wid  = tid >> 6;
    const int wr   = wid >> 2;        // 0..1
    const int wc   = wid & 3;         // 0..3
    const int la   = lane & 31;
    const int lh   = lane >> 5;

    f32x16 acc[4][2] = {};            // [mb][nb]

    const char* wbA  = wb2 + (size_t)co_tile * NT * 32768;
    const char* xs2b = xs2 + (size_t)b * 8 * 8 * PLANEB + (size_t)l0 * 16;

    const int ldsW = wid * 4096 + lane * 16;          // dest base within tile
    const size_t bS0 = (size_t)wid * PLANEB + lane * 16;

    // fragment read bases (kslot-major: addr = (s*2+lh)*4096 + row*16)
    const char* pAr = &sA[0][0] + lh * 4096 + wr * 512 + la * 16;
    const char* pBr = &sB[0][0] + lh * 4096 + wc * 1024 + la * 16;

#define BAR()    __builtin_amdgcn_s_barrier()
#define SCHED0() __builtin_amdgcn_sched_barrier(0)
#define LGKM0()  asm volatile("s_waitcnt lgkmcnt(0)" ::: "memory")

#define GL(src_, dst_) __builtin_amdgcn_global_load_lds(                                     \
    (const __attribute__((address_space(1))) unsigned int*)(src_),                           \
    (__attribute__((address_space(3))) unsigned int*)(dst_), 16, 0, 0)

    // stage unit u of K-tile c: u0=B rows0-127, u1=B rows128-255, u2=A h0, u3=A h1
    // wave wid stages kslot=wid; 2 instrs (64 rows each), src AND dest 1KB-contiguous
#define STAGEU(buf_, c_, u_) do {                                                            \
    int tap_ = (c_) % KW;  int q_ = (c_) / KW;                                               \
    if ((u_) < 2) {                                                                          \
        const char* s_ = xs2b + (size_t)q_ * (8 * PLANEB) + bS0                              \
                         + (size_t)(tap_ + (u_) * 128) * 16;                                 \
        char* d_ = &sB[buf_][0] + ldsW + (u_) * 2048;                                        \
        GL(s_, d_);  GL(s_ + 1024, d_ + 1024);                                               \
    } else {                                                                                 \
        const char* s_ = wbA + (size_t)(c_) * 32768 + ldsW + ((u_) & 1) * 2048;              \
        char* d_ = &sA[buf_][0] + ldsW + ((u_) & 1) * 2048;                                  \
        GL(s_, d_);  GL(s_ + 1024, d_ + 1024);                                               \
    } } while (0)

#define LDA(d_, buf_, mb_, s_) d_ = *(const bf16x8*)(pAr + (buf_) * 32768 + (s_) * 8192 + (mb_) * 1024)
#define LDB(d_, buf_, nb_, s_) d_ = *(const bf16x8*)(pBr + (buf_) * 32768 + (s_) * 8192 + (nb_) * 512)

#define MFMA8(MB_, B00_, B01_, B10_, B11_) do {                                              \
    __builtin_amdgcn_s_setprio(1);                                                           \
    acc[(MB_)  ][0] = __builtin_amdgcn_mfma_f32_32x32x16_bf16(a0_, B00_, acc[(MB_)  ][0],0,0,0); \
    acc[(MB_)  ][1] = __builtin_amdgcn_mfma_f32_32x32x16_bf16(a0_, B01_, acc[(MB_)  ][1],0,0,0); \
    acc[(MB_)+1][0] = __builtin_amdgcn_mfma_f32_32x32x16_bf16(a2_, B00_, acc[(MB_)+1][0],0,0,0); \
    acc[(MB_)+1][1] = __builtin_amdgcn_mfma_f32_32x32x16_bf16(a2_, B01_, acc[(MB_)+1][1],0,0,0); \
    acc[(MB_)  ][0] = __builtin_amdgcn_mfma_f32_32x32x16_bf16(a1_, B10_, acc[(MB_)  ][0],0,0,0); \
    acc[(MB_)  ][1] = __builtin_amdgcn_mfma_f32_32x32x16_bf16(a1_, B11_, acc[(MB_)  ][1],0,0,0); \
    acc[(MB_)+1][0] = __builtin_amdgcn_mfma_f32_32x32x16_bf16(a3_, B10_, acc[(MB_)+1][0],0,0,0); \
    acc[(MB_)+1][1] = __builtin_amdgcn_mfma_f32_32x32x16_bf16(a3_, B11_, acc[(MB_)+1][1],0,0,0); \
    __builtin_amdgcn_s_setprio(0);                                                           \
    } while (0)

    // prologue: stage all 4 units of tile 0; first 3 must land before p0 reads
    STAGEU(0, 0, 0); STAGEU(0, 0, 1); STAGEU(0, 0, 2); STAGEU(0, 0, 3);
    asm volatile("s_waitcnt vmcnt(2)" ::: "memory");
    BAR();

    bf16x8 b00, b01, b10, b11, b20, b21, b30, b31;   // B[s][n], live across the tile
    bf16x8 a0_, a1_, a2_, a3_;

    #pragma unroll 1
    for (int c = 0; c < NT - 1; ++c) {
        const int buf = c & 1, nb = buf ^ 1;
        // ---- p0: all B + A(mb0-1, s0-1); stage u0(next) ----
        SCHED0();
        LDB(b00, buf, 0, 0); LDB(b01, buf, 1, 0);
        LDB(b10, buf, 0, 1); LDB(b11, buf, 1, 1);
        LDB(b20, buf, 0, 2); LDB(b21, buf, 1, 2);
        LDB(b30, buf, 0, 3); LDB(b31, buf, 1, 3);
        LDA(a0_, buf, 0, 0); LDA(a1_, buf, 0, 1); LDA(a2_, buf, 1, 0); LDA(a3_, buf, 1, 1);
        STAGEU(nb, c + 1, 0);
        BAR(); LGKM0(); SCHED0();
        MFMA8(0, b00, b01, b10, b11);
        // ---- p1: A(mb0-1, s2-3); stage u1(next); wait for Ah1(cur) ----
        SCHED0();
        LDA(a0_, buf, 0, 2); LDA(a1_, buf, 0, 3); LDA(a2_, buf, 1, 2); LDA(a3_, buf, 1, 3);
        STAGEU(nb, c + 1, 1);
        asm volatile("s_waitcnt vmcnt(4)" ::: "memory");
        BAR(); LGKM0(); SCHED0();
        MFMA8(0, b20, b21, b30, b31);
        // ---- p2: A(mb2-3, s0-1); stage u2(next) ----
        SCHED0();
        LDA(a0_, buf, 2, 0); LDA(a1_, buf, 2, 1); LDA(a2_, buf, 3, 0); LDA(a3_, buf, 3, 1);
        STAGEU(nb, c + 1, 2);
        BAR(); LGKM0(); SCHED0();
        MFMA8(2, b00, b01, b10, b11);
        // ---- p3: A(mb2-3, s2-3); stage u3(next); wait for u0-u2(next) ----
        SCHED0();
        LDA(a0_, buf, 2, 2); LDA(a1_, buf, 2, 3); LDA(a2_, buf, 3, 2); LDA(a3_, buf, 3, 3);
        STAGEU(nb, c + 1, 3);
        asm volatile("s_waitcnt vmcnt(2)" ::: "memory");
        BAR(); LGKM0(); SCHED0();
        MFMA8(2, b20, b21, b30, b31);
    }
    // ---- peeled tail tile 23 (no stages); drain u3 with vmcnt(0) before mb2-3 reads ----
    {
        const int buf = (NT - 1) & 1;
        SCHED0();
        LDB(b00, buf, 0, 0); LDB(b01, buf, 1, 0);
        LDB(b10, buf, 0, 1); LDB(b11, buf, 1, 1);
        LDB(b20, buf, 0, 2); LDB(b21, buf, 1, 2);
        LDB(b30, buf, 0, 3); LDB(b31, buf, 1, 3);
        LDA(a0_, buf, 0, 0); LDA(a1_, buf, 0, 1); LDA(a2_, buf, 1, 0); LDA(a3_, buf, 1, 1);
        BAR(); LGKM0(); SCHED0();
        MFMA8(0, b00, b01, b10, b11);
        SCHED0();
        LDA(a0_, buf, 0, 2); LDA(a1_, buf, 0, 3); LDA(a2_, buf, 1, 2); LDA(a3_, buf, 1, 3);
        asm volatile("s_waitcnt vmcnt(0)" ::: "memory");
        BAR(); LGKM0(); SCHED0();
        MFMA8(0, b20, b21, b30, b31);
        SCHED0();
        LDA(a0_, buf, 2, 0); LDA(a1_, buf, 2, 1); LDA(a2_, buf, 3, 0); LDA(a3_, buf, 3, 1);
        BAR(); LGKM0(); SCHED0();
        MFMA8(2, b00, b01, b10, b11);
        SCHED0();
        LDA(a0_, buf, 2, 2); LDA(a1_, buf, 2, 3); LDA(a2_, buf, 3, 2); LDA(a3_, buf, 3, 3);
        LGKM0(); SCHED0();
        MFMA8(2, b20, b21, b30, b31);
    }
#undef STAGEU
#undef LDA
#undef LDB
#undef MFMA8
#undef GL

    // epilogue: D layout (32x32): col = lane&31, row = (rg&3) + 8*(rg>>2) + 4*(lane>>5)
    const float sc = scale_p[0];
    #pragma unroll
    for (int mb = 0; mb < 4; ++mb) {
        const int coB = co0 + mb * 64 + wr * 32 + 4 * lh;
        #pragma unroll
        for (int rg = 0; rg < 16; ++rg) {
            int co = coB + (rg & 3) + 8 * (rg >> 2);
            float bv = bias[co];
            size_t orow = ((size_t)b * COUT + co) * LEN + l0 + wc * 64 + la;
            out[orow]      = sc * acc[mb][0][rg] + bv;
            out[orow + 32] = sc * acc[mb][1][rg] + bv;
        }
    }
}

// ---- standalone wconv (fallback path only; row-major wb layout) ----
__global__ __launch_bounds__(256) void wconv_kernel(const int* __restrict__ q,
                                                    unsigned short* __restrict__ wb) {
    int idx = blockIdx.x * 256 + threadIdx.x;
    if (idx >= WB_ELEMS) return;
    int co = idx / (KW * CIN);
    int r  = idx - co * (KW * CIN);
    int t  = r >> 9;
    int ci = r & 511;
    wb[idx] = f2bf((float)q[(co * CIN + ci) * KW + t]);
}

// ---- fallback (no x prepass) — only if ws too small ----
__global__ __launch_bounds__(256, 2) void conv_fb_kernel(
    const float* __restrict__ x,
    const unsigned short* __restrict__ wb,
    const float* __restrict__ scale_p,
    const float* __restrict__ bias,
    float* __restrict__ out)
{
    __shared__ char xT[132 * 128];
    const int bid = blockIdx.x;
    const int logical = (bid & 7) * 512 + (bid >> 3);
    const int co_tile = logical & 3;
    const int n_tile  = logical >> 2;
    const int b   = n_tile >> 6;
    const int l0  = (n_tile & 63) * 128;
    const int co0 = co_tile * 128;
    const int tid  = threadIdx.x;
    const int lane = tid & 63;
    const int wid  = tid >> 6;
    const int wr = wid >> 1, wc = wid & 1;
    const int lhi = lane >> 4;
    const int llo = lane & 15;
    f32x4 acc[4][4] = {};
    const float* xb = x + (size_t)b * CIN * LEN;

    for (int ci0 = 0; ci0 < CIN; ci0 += 64) {
        __syncthreads();
        for (int it = tid; it < 132 * 8; it += 256) {
            int c = it % 132;
            int o = it / 132;
            int l = l0 - 1 + c;
            float v[8];
            if (l >= 0 && l < LEN) {
                const float* src = xb + (size_t)(ci0 + o * 8) * LEN + l;
                #pragma unroll
                for (int j = 0; j < 8; ++j) v[j] = src[(size_t)j * LEN];
            } else {
                #pragma unroll
                for (int j = 0; j < 8; ++j) v[j] = 0.f;
            }
            union { bf16x8 v8; unsigned short s[8]; } pk;
            #pragma unroll
            for (int j = 0; j < 8; ++j) pk.s[j] = f2bf(v[j]);
            int byte = c * 128 + ((o * 16) ^ ((c & 7) << 4));
            *reinterpret_cast<bf16x8*>(xT + byte) = pk.v8;
        }
        __syncthreads();
        #pragma unroll
        for (int t = 0; t < KW; ++t) {
            #pragma unroll
            for (int s = 0; s < 2; ++s) {
                bf16x8 af[4];
                #pragma unroll
                for (int m = 0; m < 4; ++m)
                    af[m] = *reinterpret_cast<const bf16x8*>(
                        wb + (size_t)(co0 + wr * 64 + m * 16 + llo) * (KW * CIN)
                           + t * CIN + ci0 + s * 32 + 8 * lhi);
                bf16x8 bfr[4];
                #pragma unroll
                for (int n = 0; n < 4; ++n) {
                    int col = wc * 64 + n * 16 + llo + t;
                    int byte = col * 128 + (((s * 32 + 8 * lhi) * 2) ^ ((col & 7) << 4));
                    bfr[n] = *reinterpret_cast<const bf16x8*>(xT + byte);
                }
                #pragma unroll
                for (int m = 0; m < 4; ++m)
                    #pragma unroll
                    for (int n = 0; n < 4; ++n)
                        acc[m][n] = __builtin_amdgcn_mfma_f32_16x16x32_bf16(af[m], bfr[n], acc[m][n], 0, 0, 0);
            }
        }
    }
    const float sc = scale_p[0];
    #pragma unroll
    for (int m = 0; m < 4; ++m) {
        #pragma unroll
        for (int j = 0; j < 4; ++j) {
            int co = co0 + wr * 64 + m * 16 + lhi * 4 + j;
            float bv = bias[co];
            size_t orow = ((size_t)b * COUT + co) * LEN + l0 + wc * 64;
            #pragma unroll
            for (int n = 0; n < 4; ++n)
                out[orow + n * 16 + llo] = sc * acc[m][n][j] + bv;
        }
    }
}

extern "C" void kernel_launch(void* const* d_in, const int* in_sizes, int n_in,
                              void* d_out, int out_size, void* d_ws, size_t ws_size,
                              hipStream_t stream) {
    const float* x    = (const float*)d_in[0];
    const int*   qw   = (const int*)d_in[1];
    const float* sc   = (const float*)d_in[2];
    const float* bias = (const float*)d_in[3];
    float* out = (float*)d_out;

    if (ws_size >= WB_BYTES + XS_BYTES) {
        char* wb2 = (char*)d_ws;
        char* xs2 = (char*)d_ws + WB_BYTES;
        prep_kernel<<<XPREP_BLOCKS + WCONV_BLOCKS, 256, 0, stream>>>(x, qw, xs2, wb2);
        conv_kernel<<<(COUT / BM2) * (NB * LEN / BN2), 512, 0, stream>>>(xs2, wb2, sc, bias, out);
    } else {
        unsigned short* wb = (unsigned short*)d_ws;
        wconv_kernel<<<WCONV_BLOCKS, 256, 0, stream>>>(qw, wb);
        conv_fb_kernel<<<4096, 256, 0, stream>>>(x, wb, sc, bias, out);
    }
}

// Round 16
// 265.149 us; speedup vs baseline: 1.1263x; 1.1263x over previous
//
#include <hip/hip_runtime.h>
#include <hip/hip_bf16.h>

#define CIN   512
#define COUT  512
#define LEN   8192
#define NB    16
#define KW    3

#define WB_ELEMS (COUT * CIN * KW)
#define WB_BYTES ((size_t)WB_ELEMS * 2)      // packed wb2, 1.5 MB
#define WCONV_BLOCKS ((WB_ELEMS + 255) / 256)

#define NT   24              // K-tiles (8 ci-chunks x 3 taps)
#define PNLP 4128            // panel plane: 258 rows x 16B
#define PNLB (8 * PNLP)      // 33024 B per panel

typedef __attribute__((ext_vector_type(4)))  float f32x4;
typedef __attribute__((ext_vector_type(8)))  float f32x8;
typedef __attribute__((ext_vector_type(16))) float f32x16;
typedef __attribute__((ext_vector_type(8)))  short bf16x8;

static __device__ __forceinline__ unsigned short f2bf(float f) {
    union { float f; unsigned u; } cv; cv.f = f;
    return (unsigned short)((cv.u + 0x7fffu + ((cv.u >> 16) & 1u)) >> 16);
}

// ---- W prep: qweight (co,ci,t) -> wb2 packed [co_tile][tile cc][kslot][row][8 bf16] ----
__global__ __launch_bounds__(256) void wprep_kernel(const int* __restrict__ q,
                                                    char* __restrict__ wb2) {
    int idx = blockIdx.x * 256 + threadIdx.x;
    if (idx >= WB_ELEMS) return;
    int co  = idx / (CIN * KW);
    int rem = idx - co * (CIN * KW);
    int ci  = rem / KW;
    int t   = rem - ci * KW;
    unsigned short v = f2bf((float)q[idx]);
    int cc = (ci >> 6) * KW + t;              // tile index (tap innermost)
    size_t byte = ((size_t)(co >> 8) * NT + cc) * 32768
                + (size_t)((ci >> 3) & 7) * 4096
                + (size_t)(co & 255) * 16 + (ci & 7) * 2;
    *(unsigned short*)(wb2 + byte) = v;
}

// ---- fused conv: 256x256 tile, 32x32x16 MFMA, kslot-major LDS, in-kernel x transpose ----
__global__ __launch_bounds__(512, 1) void conv_kernel(
    const float* __restrict__ x,
    const char* __restrict__ wb2,
    const float* __restrict__ scale_p,
    const float* __restrict__ bias,
    float* __restrict__ out)
{
    __shared__ char sA[2][32768];    // A: [kslot][row][16B], dbuf
    __shared__ char sP[2][PNLB];     // x panels: [kslot][258 prow][16B], dbuf

    const int bid = blockIdx.x;
    const int logical = (bid & 7) * 128 + (bid >> 3);   // XCD swizzle; co fastest
    const int co_tile = logical & 1;
    const int l_tile  = logical >> 1;
    const int b   = l_tile >> 5;
    const int l0  = (l_tile & 31) * 256;
    const int co0 = co_tile * 256;

    const int tid  = threadIdx.x;
    const int lane = tid & 63;
    const int wid  = tid >> 6;
    const int wr   = wid >> 2;        // 0..1
    const int wc   = wid & 3;         // 0..3
    const int la   = lane & 31;
    const int lh   = lane >> 5;

    f32x16 acc[4][2] = {};

    const float* xb  = x + (size_t)b * CIN * LEN;
    const char*  wbA = wb2 + (size_t)co_tile * NT * 32768;

    const int ldsW = wid * 4096 + lane * 16;
    char* const sA0 = &sA[0][0];
    char* const sP0 = &sP[0][0];

    // fragment read bases
    const char* pAr = sA0 + lh * 4096 + wr * 512 + la * 16;

#define BAR()    __builtin_amdgcn_s_barrier()
#define SCHED0() __builtin_amdgcn_sched_barrier(0)
#define LGKM0()  asm volatile("s_waitcnt lgkmcnt(0)" ::: "memory")
#define VMC0()   asm volatile("s_waitcnt vmcnt(0)" ::: "memory")

#define GL(src_, dst_) __builtin_amdgcn_global_load_lds(                                     \
    (const __attribute__((address_space(1))) unsigned int*)(src_),                           \
    (__attribute__((address_space(3))) unsigned int*)(dst_), 16, 0, 0)

    // stage A tile C1_ into buffer offset NBO_ (4 instrs, fully linear src/dst)
#define AGL4(NBO_, C1_) do {                                                                 \
    const char* s_ = wbA + (size_t)(C1_) * 32768 + ldsW;                                     \
    char* d_ = sA0 + (NBO_) + ldsW;                                                          \
    GL(s_, d_); GL(s_ + 1024, d_ + 1024); GL(s_ + 2048, d_ + 2048); GL(s_ + 3072, d_ + 3072);\
    } while (0)

    // B (x) reg staging: unit S (rows lane+64S), wave wid owns kslot wid (8 ci)
#define BLOADU(S_, U_, XP_) do {                                                             \
    int row_ = lane + (S_) * 64;                                                             \
    int l_   = l0 - 1 + row_;                                                                \
    _Pragma("unroll") for (int j_ = 0; j_ < 8; ++j_) U_[j_] = 0.f;                           \
    if (row_ < 258 && (unsigned)l_ < (unsigned)LEN) {                                        \
        const float* p_ = (XP_) + (size_t)(wid * 8) * LEN + l_;                              \
        _Pragma("unroll") for (int j_ = 0; j_ < 8; ++j_) U_[j_] = p_[(size_t)j_ * LEN];      \
    } } while (0)

#define BPACKU(S_, U_, PW_) do {                                                             \
    int row_ = lane + (S_) * 64;                                                             \
    if (row_ < 258) {                                                                        \
        union { bf16x8 v; unsigned short s[8]; } pk_;                                        \
        _Pragma("unroll") for (int j_ = 0; j_ < 8; ++j_) pk_.s[j_] = f2bf(U_[j_]);           \
        *(bf16x8*)((PW_) + wid * PNLP + row_ * 16) = pk_.v;                                  \
    } } while (0)

    // B fragment reads for tap T_ from panel pbR (all 8, conflict-free contiguous)
#define LDB8(PBR_, T_) do {                                                                  \
    const char* p_ = (PBR_) + lh * PNLP + (wc * 64 + la + (T_)) * 16;                        \
    b00 = *(const bf16x8*)(p_);               b01 = *(const bf16x8*)(p_ + 512);              \
    b10 = *(const bf16x8*)(p_ + 8256);        b11 = *(const bf16x8*)(p_ + 8256 + 512);       \
    b20 = *(const bf16x8*)(p_ + 16512);       b21 = *(const bf16x8*)(p_ + 16512 + 512);      \
    b30 = *(const bf16x8*)(p_ + 24768);       b31 = *(const bf16x8*)(p_ + 24768 + 512);      \
    } while (0)

#define LDA4(BUFO_, MB_, S_) do {                                                            \
    const char* p_ = pAr + (BUFO_);                                                          \
    a0_ = *(const bf16x8*)(p_ + (S_) * 8192     + (MB_) * 1024);                             \
    a1_ = *(const bf16x8*)(p_ + ((S_)+1) * 8192 + (MB_) * 1024);                             \
    a2_ = *(const bf16x8*)(p_ + (S_) * 8192     + ((MB_)+1) * 1024);                         \
    a3_ = *(const bf16x8*)(p_ + ((S_)+1) * 8192 + ((MB_)+1) * 1024);                         \
    } while (0)

#define MFMA8(MB_, B00_, B01_, B10_, B11_) do {                                              \
    __builtin_amdgcn_s_setprio(1);                                                           \
    acc[(MB_)  ][0] = __builtin_amdgcn_mfma_f32_32x32x16_bf16(a0_, B00_, acc[(MB_)  ][0],0,0,0); \
    acc[(MB_)  ][1] = __builtin_amdgcn_mfma_f32_32x32x16_bf16(a0_, B01_, acc[(MB_)  ][1],0,0,0); \
    acc[(MB_)+1][0] = __builtin_amdgcn_mfma_f32_32x32x16_bf16(a2_, B00_, acc[(MB_)+1][0],0,0,0); \
    acc[(MB_)+1][1] = __builtin_amdgcn_mfma_f32_32x32x16_bf16(a2_, B01_, acc[(MB_)+1][1],0,0,0); \
    acc[(MB_)  ][0] = __builtin_amdgcn_mfma_f32_32x32x16_bf16(a1_, B10_, acc[(MB_)  ][0],0,0,0); \
    acc[(MB_)  ][1] = __builtin_amdgcn_mfma_f32_32x32x16_bf16(a1_, B11_, acc[(MB_)  ][1],0,0,0); \
    acc[(MB_)+1][0] = __builtin_amdgcn_mfma_f32_32x32x16_bf16(a3_, B10_, acc[(MB_)+1][0],0,0,0); \
    acc[(MB_)+1][1] = __builtin_amdgcn_mfma_f32_32x32x16_bf16(a3_, B11_, acc[(MB_)+1][1],0,0,0); \
    __builtin_amdgcn_s_setprio(0);                                                           \
    } while (0)

    bf16x8 b00, b01, b10, b11, b20, b21, b30, b31;
    bf16x8 a0_, a1_, a2_, a3_;
    f32x8 u0, u1, u2;

    // ---------- prologue: A tile 0 + full panel 0 ----------
    AGL4(0, 0);
    BLOADU(0, u0, xb); BLOADU(1, u1, xb);
    BPACKU(0, u0, sP0); BLOADU(2, u0, xb);
    BPACKU(1, u1, sP0); BLOADU(3, u1, xb);
    BPACKU(2, u0, sP0); BLOADU(4, u0, xb);
    BPACKU(3, u1, sP0);
    BPACKU(4, u0, sP0);
    VMC0(); LGKM0();
    BAR();

    #pragma unroll 1
    for (int qq = 0; qq < 7; ++qq) {
        const int c0   = 3 * qq;
        const int bo0  = (c0 & 1) << 15;          // tile c0 buffer offset
        const int bo1  = bo0 ^ 32768;             // tile c0+1
        const char* pbR = sP0 + (qq & 1) * PNLB;
        char*       pbW = sP0 + ((qq + 1) & 1) * PNLB;
        const float* xn = xb + (size_t)(qq + 1) * (64 * LEN);

        // ======== tile t0 (c0, tap0, reads bo0, stages into bo1) ========
        SCHED0();
        AGL4(bo1, c0 + 1);
        BLOADU(0, u0, xn);
        LDB8(pbR, 0);
        LDA4(bo0, 0, 0);
        BAR(); LGKM0(); SCHED0();
        MFMA8(0, b00, b01, b10, b11);
        SCHED0();
        BLOADU(1, u1, xn);
        LDA4(bo0, 0, 2);
        BAR(); LGKM0(); SCHED0();
        MFMA8(0, b20, b21, b30, b31);
        SCHED0();
        BLOADU(2, u2, xn); BPACKU(0, u0, pbW);    // auto-vmcnt on L0 drains t0p0 AGLs
        LDA4(bo0, 2, 0);
        BAR(); LGKM0(); SCHED0();
        MFMA8(2, b00, b01, b10, b11);
        SCHED0();
        BPACKU(1, u1, pbW);
        LDA4(bo0, 2, 2);
        BAR(); LGKM0(); SCHED0();
        MFMA8(2, b20, b21, b30, b31);
        // ======== tile t1 (c0+1, tap1, reads bo1, stages into bo0) ========
        SCHED0();
        AGL4(bo0, c0 + 2);
        BLOADU(3, u0, xn);
        LDB8(pbR, 1);
        LDA4(bo1, 0, 0);
        BAR(); LGKM0(); SCHED0();
        MFMA8(0, b00, b01, b10, b11);
        SCHED0();
        BLOADU(4, u1, xn); BPACKU(2, u2, pbW);
        LDA4(bo1, 0, 2);
        BAR(); LGKM0(); SCHED0();
        MFMA8(0, b20, b21, b30, b31);
        SCHED0();
        BPACKU(3, u0, pbW);                       // auto-vmcnt on L3 drains t1p0 AGLs
        LDA4(bo1, 2, 0);
        BAR(); LGKM0(); SCHED0();
        MFMA8(2, b00, b01, b10, b11);
        SCHED0();
        BPACKU(4, u1, pbW);
        LDA4(bo1, 2, 2);
        BAR(); LGKM0(); SCHED0();
        MFMA8(2, b20, b21, b30, b31);
        // ======== tile t2 (c0+2, tap2, reads bo0, stages into bo1) ========
        SCHED0();
        AGL4(bo1, c0 + 3);
        LDB8(pbR, 2);
        LDA4(bo0, 0, 0);
        BAR(); LGKM0(); SCHED0();
        MFMA8(0, b00, b01, b10, b11);
        SCHED0();
        LDA4(bo0, 0, 2);
        BAR(); LGKM0(); SCHED0();
        MFMA8(0, b20, b21, b30, b31);
        SCHED0();
        LDA4(bo0, 2, 0);
        BAR(); LGKM0(); SCHED0();
        MFMA8(2, b00, b01, b10, b11);
        SCHED0();
        LDA4(bo0, 2, 2);
        VMC0(); LGKM0();                           // drain AGL(c0+3) + publish panel writes
        BAR(); SCHED0();
        MFMA8(2, b20, b21, b30, b31);
    }
    // ---------- chunk 7: tiles 21,22,23 read panel[1]; no B staging ----------
    {
        const char* pbR = sP0 + PNLB;
        // tile 21 (buf: 21&1=1 -> bo 32768), stages tile 22 into bo 0
        SCHED0();
        AGL4(0, 22);
        LDB8(pbR, 0);
        LDA4(32768, 0, 0);
        BAR(); LGKM0(); SCHED0();
        MFMA8(0, b00, b01, b10, b11);
        SCHED0(); LDA4(32768, 0, 2);
        BAR(); LGKM0(); SCHED0();
        MFMA8(0, b20, b21, b30, b31);
        SCHED0(); LDA4(32768, 2, 0);
        BAR(); LGKM0(); SCHED0();
        MFMA8(2, b00, b01, b10, b11);
        SCHED0(); LDA4(32768, 2, 2);
        VMC0(); LGKM0(); BAR(); SCHED0();
        MFMA8(2, b20, b21, b30, b31);
        // tile 22 (bo 0), stages tile 23 into bo 32768
        SCHED0();
        AGL4(32768, 23);
        LDB8(pbR, 1);
        LDA4(0, 0, 0);
        BAR(); LGKM0(); SCHED0();
        MFMA8(0, b00, b01, b10, b11);
        SCHED0(); LDA4(0, 0, 2);
        BAR(); LGKM0(); SCHED0();
        MFMA8(0, b20, b21, b30, b31);
        SCHED0(); LDA4(0, 2, 0);
        BAR(); LGKM0(); SCHED0();
        MFMA8(2, b00, b01, b10, b11);
        SCHED0(); LDA4(0, 2, 2);
        VMC0(); LGKM0(); BAR(); SCHED0();
        MFMA8(2, b20, b21, b30, b31);
        // tile 23 (bo 32768), no stages
        SCHED0();
        LDB8(pbR, 2);
        LDA4(32768, 0, 0);
        LGKM0(); SCHED0();
        MFMA8(0, b00, b01, b10, b11);
        SCHED0(); LDA4(32768, 0, 2);
        LGKM0(); SCHED0();
        MFMA8(0, b20, b21, b30, b31);
        SCHED0(); LDA4(32768, 2, 0);
        LGKM0(); SCHED0();
        MFMA8(2, b00, b01, b10, b11);
        SCHED0(); LDA4(32768, 2, 2);
        LGKM0(); SCHED0();
        MFMA8(2, b20, b21, b30, b31);
    }
#undef AGL4
#undef BLOADU
#undef BPACKU
#undef LDB8
#undef LDA4
#undef MFMA8
#undef GL

    // epilogue: D (32x32): col = lane&31, row = (rg&3) + 8*(rg>>2) + 4*(lane>>5)
    const float sc = scale_p[0];
    #pragma unroll
    for (int mb = 0; mb < 4; ++mb) {
        const int coB = co0 + mb * 64 + wr * 32 + 4 * lh;
        #pragma unroll
        for (int rg = 0; rg < 16; ++rg) {
            int co = coB + (rg & 3) + 8 * (rg >> 2);
            float bv = bias[co];
            size_t orow = ((size_t)b * COUT + co) * LEN + l0 + wc * 64 + la;
            out[orow]      = sc * acc[mb][0][rg] + bv;
            out[orow + 32] = sc * acc[mb][1][rg] + bv;
        }
    }
}

// ---- fallback pair (only if ws can't hold 1.5 MB — effectively never) ----
__global__ __launch_bounds__(256) void wconv_kernel(const int* __restrict__ q,
                                                    unsigned short* __restrict__ wb) {
    int idx = blockIdx.x * 256 + threadIdx.x;
    if (idx >= WB_ELEMS) return;
    int co = idx / (KW * CIN);
    int r  = idx - co * (KW * CIN);
    int t  = r >> 9;
    int ci = r & 511;
    wb[idx] = f2bf((float)q[(co * CIN + ci) * KW + t]);
}

__global__ __launch_bounds__(256, 2) void conv_fb_kernel(
    const float* __restrict__ x,
    const unsigned short* __restrict__ wb,
    const float* __restrict__ scale_p,
    const float* __restrict__ bias,
    float* __restrict__ out)
{
    __shared__ char xT[132 * 128];
    const int bid = blockIdx.x;
    const int logical = (bid & 7) * 512 + (bid >> 3);
    const int co_tile = logical & 3;
    const int n_tile  = logical >> 2;
    const int b   = n_tile >> 6;
    const int l0  = (n_tile & 63) * 128;
    const int co0 = co_tile * 128;
    const int tid  = threadIdx.x;
    const int lane = tid & 63;
    const int wid  = tid >> 6;
    const int wr = wid >> 1, wc = wid & 1;
    const int lhi = lane >> 4;
    const int llo = lane & 15;
    f32x4 acc[4][4] = {};
    const float* xb = x + (size_t)b * CIN * LEN;

    for (int ci0 = 0; ci0 < CIN; ci0 += 64) {
        __syncthreads();
        for (int it = tid; it < 132 * 8; it += 256) {
            int c = it % 132;
            int o = it / 132;
            int l = l0 - 1 + c;
            float v[8];
            if (l >= 0 && l < LEN) {
                const float* src = xb + (size_t)(ci0 + o * 8) * LEN + l;
                #pragma unroll
                for (int j = 0; j < 8; ++j) v[j] = src[(size_t)j * LEN];
            } else {
                #pragma unroll
                for (int j = 0; j < 8; ++j) v[j] = 0.f;
            }
            union { bf16x8 v8; unsigned short s[8]; } pk;
            #pragma unroll
            for (int j = 0; j < 8; ++j) pk.s[j] = f2bf(v[j]);
            int byte = c * 128 + ((o * 16) ^ ((c & 7) << 4));
            *reinterpret_cast<bf16x8*>(xT + byte) = pk.v8;
        }
        __syncthreads();
        #pragma unroll
        for (int t = 0; t < KW; ++t) {
            #pragma unroll
            for (int s = 0; s < 2; ++s) {
                bf16x8 af[4];
                #pragma unroll
                for (int m = 0; m < 4; ++m)
                    af[m] = *reinterpret_cast<const bf16x8*>(
                        wb + (size_t)(co0 + wr * 64 + m * 16 + llo) * (KW * CIN)
                           + t * CIN + ci0 + s * 32 + 8 * lhi);
                bf16x8 bfr[4];
                #pragma unroll
                for (int n = 0; n < 4; ++n) {
                    int col = wc * 64 + n * 16 + llo + t;
                    int byte = col * 128 + (((s * 32 + 8 * lhi) * 2) ^ ((col & 7) << 4));
                    bfr[n] = *reinterpret_cast<const bf16x8*>(xT + byte);
                }
                #pragma unroll
                for (int m = 0; m < 4; ++m)
                    #pragma unroll
                    for (int n = 0; n < 4; ++n)
                        acc[m][n] = __builtin_amdgcn_mfma_f32_16x16x32_bf16(af[m], bfr[n], acc[m][n], 0, 0, 0);
            }
        }
    }
    const float sc = scale_p[0];
    #pragma unroll
    for (int m = 0; m < 4; ++m) {
        #pragma unroll
        for (int j = 0; j < 4; ++j) {
            int co = co0 + wr * 64 + m * 16 + lhi * 4 + j;
            float bv = bias[co];
            size_t orow = ((size_t)b * COUT + co) * LEN + l0 + wc * 64;
            #pragma unroll
            for (int n = 0; n < 4; ++n)
                out[orow + n * 16 + llo] = sc * acc[m][n][j] + bv;
        }
    }
}

extern "C" void kernel_launch(void* const* d_in, const int* in_sizes, int n_in,
                              void* d_out, int out_size, void* d_ws, size_t ws_size,
                              hipStream_t stream) {
    const float* x    = (const float*)d_in[0];
    const int*   qw   = (const int*)d_in[1];
    const float* sc   = (const float*)d_in[2];
    const float* bias = (const float*)d_in[3];
    float* out = (float*)d_out;

    if (ws_size >= WB_BYTES) {
        char* wb2 = (char*)d_ws;
        wprep_kernel<<<WCONV_BLOCKS, 256, 0, stream>>>(qw, wb2);
        conv_kernel<<<1024, 512, 0, stream>>>(x, wb2, sc, bias, out);
    } else {
        unsigned short* wb = (unsigned short*)d_ws;
        wconv_kernel<<<WCONV_BLOCKS, 256, 0, stream>>>(qw, wb);
        conv_fb_kernel<<<4096, 256, 0, stream>>>(x, wb, sc, bias, out);
    }
}